// Round 1
// 333.741 us; speedup vs baseline: 3.1030x; 3.1030x over previous
//
#include <hip/hip_runtime.h>
#include <hip/hip_bf16.h>
#include <stdint.h>

typedef short s8v __attribute__((ext_vector_type(8)));
typedef float f4v __attribute__((ext_vector_type(4)));

__device__ __forceinline__ void async_copy16(const void* gsrc, void* lds_dst) {
  __builtin_amdgcn_global_load_lds(
      (const __attribute__((address_space(1))) uint32_t*)(uintptr_t)gsrc,
      (__attribute__((address_space(3))) uint32_t*)(uint32_t)(uintptr_t)lds_dst,
      16, 0, 0);
}

// ---------------- W pack: [co][ci][kh][kw] fp32 -> [kh*5+kw][co][ci] bf16 ----------------
__global__ void wpack_kernel(const float* __restrict__ W, __hip_bfloat16* __restrict__ Wr) {
  int i = blockIdx.x * 256 + threadIdx.x;  // < 819200
  int ci = i & 255;
  int rest = i >> 8;
  int co = rest & 127;
  int pos = rest >> 7;  // kh*5+kw
  Wr[i] = __float2bfloat16(W[(co * 256 + ci) * 25 + pos]);
}

// ---------------- Upsample: x NCHW fp32 (8,256,64,64) -> up NHWC bf16 (8,128,128,256) ----------------
// grid: b(8) x cb(4,64ch) x ohb(8,16 rows) x owb(2,64 cols) = 512 blocks
__global__ __launch_bounds__(256, 2) void upsample_kernel(const float* __restrict__ x,
                                                          __hip_bfloat16* __restrict__ up) {
  __shared__ __hip_bfloat16 lx[10 * 48 * 66];  // [ih 10][iw 48][c 64 + 2 pad]
  const int tid = threadIdx.x;
  const int bx = blockIdx.x;
  const int owb = bx & 1;
  const int ohb = (bx >> 1) & 7;
  const int cb = (bx >> 4) & 3;
  const int b = bx >> 6;
  const int oh0 = ohb * 16, ow0 = owb * 64, c0 = cb * 64;
  const int ih0 = (oh0 >> 1) - 1;                    // may be -1
  const int iw_lo = (ow0 >> 1) - 1;
  const int aligned = (iw_lo < 0 ? 0 : iw_lo) & ~15; // 0 or 16

  for (int i = tid; i < 64 * 10 * 12; i += 256) {    // float4 loads along iw
    int c = i / 120;
    int rem = i - c * 120;
    int r = rem / 12;
    int w4 = (rem - r * 12) * 4;
    int gr = ih0 + r;
    gr = gr < 0 ? 0 : (gr > 63 ? 63 : gr);
    const float4 v = *(const float4*)&x[(((b * 256 + c0 + c) * 64) + gr) * 64 + aligned + w4];
    int base = (r * 48 + w4) * 66 + c;
    lx[base]       = __float2bfloat16(v.x);
    lx[base + 66]  = __float2bfloat16(v.y);
    lx[base + 132] = __float2bfloat16(v.z);
    lx[base + 198] = __float2bfloat16(v.w);
  }
  __syncthreads();

  const int c_l = tid & 63;
  const int owq = tid >> 6;
  for (int it = 0; it < 256; ++it) {
    int oh_l = it >> 4;
    int ow_l = (it & 15) * 4 + owq;
    int oh = oh0 + oh_l, ow = ow0 + ow_l;
    int ihA = (oh >> 1) - ((oh & 1) ^ 1);            // first tap row
    float wh = (oh & 1) ? 0.75f : 0.25f;             // its weight
    int iwA = (ow >> 1) - ((ow & 1) ^ 1);
    float wwt = (ow & 1) ? 0.75f : 0.25f;
    int r0 = ihA - ih0;                               // slot content is pre-clamped
    int w0 = (iwA < 0 ? 0 : iwA) - aligned;
    int w1t = iwA + 1; w1t = w1t > 63 ? 63 : w1t;
    int w1 = w1t - aligned;
    float t00 = __bfloat162float(lx[(r0 * 48 + w0) * 66 + c_l]);
    float t01 = __bfloat162float(lx[(r0 * 48 + w1) * 66 + c_l]);
    float t10 = __bfloat162float(lx[((r0 + 1) * 48 + w0) * 66 + c_l]);
    float t11 = __bfloat162float(lx[((r0 + 1) * 48 + w1) * 66 + c_l]);
    float v = wh * (wwt * t00 + (1.f - wwt) * t01) + (1.f - wh) * (wwt * t10 + (1.f - wwt) * t11);
    up[(((size_t)(b * 128 + oh) * 128) + ow) * 256 + c0 + c_l] = __float2bfloat16(v);
  }
}

// ---------------- Conv: implicit GEMM, M=512 (4 out rows) x N=128 couts, MFMA bf16 ----------------
// grid: 256 blocks (1 per CU) = b(8) x ohg(32, 4-row groups), 512 threads (8 waves: 4 rows x 2 cout-halves)
// lA: 6-slot circular window of up rows [132 iw+halo][64 ch], XOR-swizzled, prefetch 1 row ahead.
// lB: double-buffered [128 cout][64 ch], next (kh,kw) prefetched before compute -> 1 barrier/round.
#define SLOTC 1056  // chunks per lA slot = 132*8
__global__ __launch_bounds__(512, 2) void conv_kernel(const __hip_bfloat16* __restrict__ up,
                                                      const __hip_bfloat16* __restrict__ Wr,
                                                      float* __restrict__ out,
                                                      float* __restrict__ gstats) {
  __shared__ __align__(16) unsigned short lA[6 * 132 * 64];  // 101376 B
  __shared__ __align__(16) unsigned short lB[2][128 * 64];   //  32768 B

  const int tid = threadIdx.x;
  const int lane = tid & 63;
  const int wave = tid >> 6;
  const int wm = wave >> 1;   // output row within 4-row group
  const int wn = wave & 1;    // cout half
  const int lane15 = lane & 15;
  const int quad = lane >> 4;
  const int wb = wave << 6;   // wave chunk base

  const int bid = blockIdx.x;
  const int orig = ((bid & 7) << 5) | (bid >> 3);  // XCD-chunked: each XCD owns one batch image
  const int b = orig >> 5;
  const int oh0 = (orig & 31) << 2;

  const f4v zero4 = {0.f, 0.f, 0.f, 0.f};

  // zero kw-halo chunks (rows 0,1,130,131) of all 6 slots; staging never touches them
  if (tid < 192) {
    int s = tid >> 5, j = tid & 31;
    int rsel = j >> 3;
    int r = (rsel < 2) ? rsel : (128 + rsel);
    *(f4v*)&lA[(s * SLOTC + r * 8 + (j & 7)) * 8] = zero4;
  }

  f4v acc[8][4];
#pragma unroll
  for (int i = 0; i < 8; ++i)
#pragma unroll
    for (int j = 0; j < 4; ++j) acc[i][j] = zero4;

  // ---- prologue: prime lA rows oh0-2..oh0+1 (cb=0) + lB pos0 (cb=0) into lB[0]
  for (int rr = 0; rr < 4; ++rr) {
    int ih = oh0 + rr - 2;
    if ((unsigned)ih < 128u) {
      int sp = ih % 6;
      const __hip_bfloat16* uprow = up + (size_t)(b * 128 + ih) * 128 * 256;
#pragma unroll
      for (int t = 0; t < 2; ++t) {
        int pl = t * 512 + wb + lane;
        int riw = pl >> 3, pc = pl & 7;
        int cq = pc ^ ((riw + 2) & 7);
        async_copy16(uprow + riw * 256 + cq * 8,
                     (void*)&lA[(sp * SLOTC + 16 + t * 512 + wb) * 8]);
      }
    }
  }
#pragma unroll
  for (int t = 0; t < 2; ++t) {
    int pl = t * 512 + wb + lane;
    int n = pl >> 3, pc = pl & 7;
    int cq = pc ^ (n & 7);
    async_copy16(Wr + n * 256 + cq * 8, (void*)&lB[0][(t * 512 + wb) * 8]);
  }
  __syncthreads();

  int buf = 0;
  for (int cb = 0; cb < 4; ++cb) {
    const int c0 = cb << 6;
    for (int kh = 0; kh < 5; ++kh) {
      const int ih = oh0 + wm + kh - 2;
      const bool rowok = (unsigned)ih < 128u;
      const int abase = rowok ? (ih % 6) * SLOTC : 0;
      for (int kw = 0; kw < 5; ++kw) {
        const int pos = kh * 5 + kw;
        if (pos < 24) {  // prefetch next round's lB into the other buffer
          const __hip_bfloat16* wrow = Wr + (size_t)(pos + 1) * 32768 + c0;
#pragma unroll
          for (int t = 0; t < 2; ++t) {
            int pl = t * 512 + wb + lane;
            int n = pl >> 3, pc = pl & 7;
            int cq = pc ^ (n & 7);
            async_copy16(wrow + n * 256 + cq * 8, (void*)&lB[buf ^ 1][(t * 512 + wb) * 8]);
          }
        }
        if (kw == 0 && kh < 4) {  // prefetch lA row needed at kh+1 (slot free since kh-2)
          int ihp = oh0 + kh + 2;
          if (ihp < 128) {
            int sp = ihp % 6;
            const __hip_bfloat16* uprow = up + (size_t)(b * 128 + ihp) * 128 * 256 + c0;
#pragma unroll
            for (int t = 0; t < 2; ++t) {
              int pl = t * 512 + wb + lane;
              int riw = pl >> 3, pc = pl & 7;
              int cq = pc ^ ((riw + 2) & 7);
              async_copy16(uprow + riw * 256 + cq * 8,
                           (void*)&lA[(sp * SLOTC + 16 + t * 512 + wb) * 8]);
            }
          }
        }
        if (rowok) {  // wave-uniform; barriers stay outside
#pragma unroll
          for (int ks = 0; ks < 2; ++ks) {
            const int cq = ks * 4 + quad;
            s8v a[8], bb[4];
#pragma unroll
            for (int mt = 0; mt < 8; ++mt) {
              int r = mt * 16 + lane15 + kw;
              a[mt] = *(const s8v*)&lA[(abase + r * 8 + (cq ^ (r & 7))) * 8];
            }
#pragma unroll
            for (int nt = 0; nt < 4; ++nt) {
              int n = (wn << 6) + nt * 16 + lane15;
              bb[nt] = *(const s8v*)&lB[buf][(n * 8 + (cq ^ (n & 7))) * 8];
            }
#pragma unroll
            for (int mt = 0; mt < 8; ++mt)
#pragma unroll
              for (int nt = 0; nt < 4; ++nt)
                acc[mt][nt] = __builtin_amdgcn_mfma_f32_16x16x32_bf16(a[mt], bb[nt], acc[mt][nt], 0, 0, 0);
          }
        }
        __syncthreads();  // drains this round's prefetches; next round reads them
        buf ^= 1;
      }
    }
    if (cb < 3) {  // cb boundary: re-prime lA window + first lB of next cb (one drain)
      const int c0n = (cb + 1) << 6;
      for (int rr = 0; rr < 4; ++rr) {
        int ihn = oh0 + rr - 2;
        if ((unsigned)ihn < 128u) {
          int sp = ihn % 6;
          const __hip_bfloat16* uprow = up + (size_t)(b * 128 + ihn) * 128 * 256 + c0n;
#pragma unroll
          for (int t = 0; t < 2; ++t) {
            int pl = t * 512 + wb + lane;
            int riw = pl >> 3, pc = pl & 7;
            int cq = pc ^ ((riw + 2) & 7);
            async_copy16(uprow + riw * 256 + cq * 8,
                         (void*)&lA[(sp * SLOTC + 16 + t * 512 + wb) * 8]);
          }
        }
      }
#pragma unroll
      for (int t = 0; t < 2; ++t) {
        int pl = t * 512 + wb + lane;
        int n = pl >> 3, pc = pl & 7;
        int cq = pc ^ (n & 7);
        async_copy16(Wr + c0n + n * 256 + cq * 8, (void*)&lB[buf ^ 1][(t * 512 + wb) * 8]);
      }
      __syncthreads();
      buf ^= 1;
    }
  }

  // ---- epilogue: direct stores from acc (D: cout=lane&15, ow=mt*16+quad*4+reg) + stats
  const int oh = oh0 + wm;
#pragma unroll
  for (int nt = 0; nt < 4; ++nt) {
    const int n = (wn << 6) + nt * 16 + lane15;
    float* oc = out + (((size_t)(b * 128 + n)) * 128 + oh) * 128;
    float s = 0.f, ss = 0.f;
#pragma unroll
    for (int mt = 0; mt < 8; ++mt) {
      f4v v = acc[mt][nt];
      *(f4v*)&oc[mt * 16 + (quad << 2)] = v;
      s += v.x + v.y + v.z + v.w;
      ss += v.x * v.x + v.y * v.y + v.z * v.z + v.w * v.w;
    }
    s += __shfl_xor(s, 16, 64); ss += __shfl_xor(ss, 16, 64);
    s += __shfl_xor(s, 32, 64); ss += __shfl_xor(ss, 32, 64);
    if (quad == 0) {
      atomicAdd(&gstats[n], s);
      atomicAdd(&gstats[128 + n], ss);
    }
  }
}

// ---------------- BN scale/bias from accumulated stats ----------------
__global__ void scalebias_kernel(const float* __restrict__ gstats, const float* __restrict__ gamma,
                                 const float* __restrict__ beta, float* __restrict__ sb) {
  int c = threadIdx.x;
  float mean = gstats[c] * (1.f / 131072.f);
  float var = gstats[128 + c] * (1.f / 131072.f) - mean * mean;
  float inv = gamma[c] * rsqrtf(var + 1e-5f);
  sb[c] = inv;
  sb[128 + c] = beta[c] - mean * inv;
}

// ---------------- Normalize + ReLU in-place on d_out ----------------
__global__ void norm_kernel(float* __restrict__ out, const float* __restrict__ sb) {
  int i = blockIdx.x * 256 + threadIdx.x;  // float4 index, 4194304 total
  f4v v = ((f4v*)out)[i];
  int c = (i >> 12) & 127;
  float sc = sb[c], bi = sb[128 + c];
  v.x = fmaxf(fmaf(v.x, sc, bi), 0.f);
  v.y = fmaxf(fmaf(v.y, sc, bi), 0.f);
  v.z = fmaxf(fmaf(v.z, sc, bi), 0.f);
  v.w = fmaxf(fmaf(v.w, sc, bi), 0.f);
  ((f4v*)out)[i] = v;
}

extern "C" void kernel_launch(void* const* d_in, const int* in_sizes, int n_in,
                              void* d_out, int out_size, void* d_ws, size_t ws_size,
                              hipStream_t stream) {
  (void)in_sizes; (void)n_in; (void)out_size; (void)ws_size;
  const float* x = (const float*)d_in[0];
  const float* W = (const float*)d_in[1];
  const float* gamma = (const float*)d_in[2];
  const float* beta = (const float*)d_in[3];
  float* out = (float*)d_out;
  char* ws = (char*)d_ws;
  __hip_bfloat16* up = (__hip_bfloat16*)ws;                       // 67,108,864 B
  __hip_bfloat16* Wr = (__hip_bfloat16*)(ws + 67108864);          // 1,638,400 B
  float* gstats = (float*)(ws + 67108864 + 1638400);              // sum[128], sumsq[128]
  float* sb = gstats + 256;                                       // scale[128], bias[128]

  hipMemsetAsync(gstats, 0, 256 * sizeof(float), stream);
  wpack_kernel<<<3200, 256, 0, stream>>>(W, Wr);
  upsample_kernel<<<512, 256, 0, stream>>>(x, up);
  conv_kernel<<<256, 512, 0, stream>>>(up, Wr, out, gstats);
  scalebias_kernel<<<1, 128, 0, stream>>>(gstats, gamma, beta, sb);
  norm_kernel<<<16384, 256, 0, stream>>>(out, sb);
}